// Round 1
// 11207.076 us; speedup vs baseline: 1.2868x; 1.2868x over previous
//
#include <hip/hip_runtime.h>
#include <math.h>

#define Bb 64
#define Tt 256
#define Vv 4096
#define Ee 512
#define Hh 1024
#define NBLK 256
#define NGRP 64
#define FSTR 16   // one flag per 64B cacheline

// ---------------- input projection: AtT[t][n][b] = sum_e wte[x[b,t]][e]*W[n][e] + bias[n]
__global__ __launch_bounds__(256) void k_proj(const int* __restrict__ x,
                                              const float* __restrict__ wte,
                                              const float* __restrict__ W,
                                              const float* __restrict__ bias,
                                              float* __restrict__ AtT) {
  __shared__ float As[16][132];
  __shared__ float Bs[16][132];
  int tid = threadIdx.x;
  int m0 = blockIdx.x * 128;
  int n0 = blockIdx.y * 128;
  int tm = tid & 15, tn = tid >> 4;
  float acc[8][8];
#pragma unroll
  for (int i = 0; i < 8; ++i)
#pragma unroll
    for (int j = 0; j < 8; ++j) acc[i][j] = 0.f;

  for (int k0 = 0; k0 < Ee; k0 += 16) {
#pragma unroll
    for (int p = 0; p < 2; ++p) {
      int id = tid + p * 256;
      int row = id >> 2, c4 = id & 3;
      int m = m0 + row;
      int tok = x[(m & 63) * Tt + (m >> 6)];
      float4 v = *(const float4*)(wte + tok * Ee + k0 + c4 * 4);
      As[c4 * 4 + 0][row] = v.x; As[c4 * 4 + 1][row] = v.y;
      As[c4 * 4 + 2][row] = v.z; As[c4 * 4 + 3][row] = v.w;
    }
#pragma unroll
    for (int p = 0; p < 2; ++p) {
      int id = tid + p * 256;
      int row = id >> 2, c4 = id & 3;
      float4 v = *(const float4*)(W + (n0 + row) * 1536 + k0 + c4 * 4);
      Bs[c4 * 4 + 0][row] = v.x; Bs[c4 * 4 + 1][row] = v.y;
      Bs[c4 * 4 + 2][row] = v.z; Bs[c4 * 4 + 3][row] = v.w;
    }
    __syncthreads();
#pragma unroll
    for (int kk = 0; kk < 16; ++kk) {
      float4 a0 = *(const float4*)&As[kk][tm * 8];
      float4 a1 = *(const float4*)&As[kk][tm * 8 + 4];
      float4 b0 = *(const float4*)&Bs[kk][tn * 8];
      float4 b1 = *(const float4*)&Bs[kk][tn * 8 + 4];
      float av[8] = {a0.x, a0.y, a0.z, a0.w, a1.x, a1.y, a1.z, a1.w};
      float bv[8] = {b0.x, b0.y, b0.z, b0.w, b1.x, b1.y, b1.z, b1.w};
#pragma unroll
      for (int i = 0; i < 8; ++i)
#pragma unroll
        for (int j = 0; j < 8; ++j)
          acc[i][j] = fmaf(av[i], bv[j], acc[i][j]);
    }
    __syncthreads();
  }
#pragma unroll
  for (int i = 0; i < 8; ++i) {
    int m = m0 + tm * 8 + i;
    int t = m >> 6, b = m & 63;
#pragma unroll
    for (int j = 0; j < 8; ++j) {
      int n = n0 + tn * 8 + j;
      AtT[(size_t)t * (Hh * Bb) + n * Bb + b] = acc[i][j] + bias[n];
    }
  }
}

// ---------------- head GEMM ------------------------------------------------------------
__global__ __launch_bounds__(256) void k_head(const float* __restrict__ A,
                                              const float* __restrict__ W,
                                              const float* __restrict__ bias,
                                              float* __restrict__ C) {
  __shared__ float As[16][132];
  __shared__ float Bs[16][132];
  int tid = threadIdx.x;
  int m0 = blockIdx.x * 128;
  int n0 = blockIdx.y * 128;
  int tm = tid & 15, tn = tid >> 4;
  float acc[8][8];
#pragma unroll
  for (int i = 0; i < 8; ++i)
#pragma unroll
    for (int j = 0; j < 8; ++j) acc[i][j] = 0.f;

  for (int k0 = 0; k0 < Hh; k0 += 16) {
#pragma unroll
    for (int p = 0; p < 2; ++p) {
      int id = tid + p * 256;
      int row = id >> 2, c4 = id & 3;
      float4 v = *(const float4*)(A + (size_t)(m0 + row) * Hh + k0 + c4 * 4);
      As[c4 * 4 + 0][row] = v.x; As[c4 * 4 + 1][row] = v.y;
      As[c4 * 4 + 2][row] = v.z; As[c4 * 4 + 3][row] = v.w;
    }
#pragma unroll
    for (int p = 0; p < 2; ++p) {
      int id = tid + p * 256;
      int row = id >> 2, c4 = id & 3;
      float4 v = *(const float4*)(W + (size_t)(n0 + row) * Hh + k0 + c4 * 4);
      Bs[c4 * 4 + 0][row] = v.x; Bs[c4 * 4 + 1][row] = v.y;
      Bs[c4 * 4 + 2][row] = v.z; Bs[c4 * 4 + 3][row] = v.w;
    }
    __syncthreads();
#pragma unroll
    for (int kk = 0; kk < 16; ++kk) {
      float4 a0 = *(const float4*)&As[kk][tm * 8];
      float4 a1 = *(const float4*)&As[kk][tm * 8 + 4];
      float4 b0 = *(const float4*)&Bs[kk][tn * 8];
      float4 b1 = *(const float4*)&Bs[kk][tn * 8 + 4];
      float av[8] = {a0.x, a0.y, a0.z, a0.w, a1.x, a1.y, a1.z, a1.w};
      float bv[8] = {b0.x, b0.y, b0.z, b0.w, b1.x, b1.y, b1.z, b1.w};
#pragma unroll
      for (int i = 0; i < 8; ++i)
#pragma unroll
        for (int j = 0; j < 8; ++j)
          acc[i][j] = fmaf(av[i], bv[j], acc[i][j]);
    }
    __syncthreads();
  }
#pragma unroll
  for (int i = 0; i < 8; ++i) {
    int m = m0 + tm * 8 + i;
#pragma unroll
    for (int jj = 0; jj < 2; ++jj) {
      int n = n0 + tn * 8 + jj * 4;
      float4 v;
      v.x = acc[i][jj * 4 + 0] + bias[n + 0];
      v.y = acc[i][jj * 4 + 1] + bias[n + 1];
      v.z = acc[i][jj * 4 + 2] + bias[n + 2];
      v.w = acc[i][jj * 4 + 3] + bias[n + 3];
      *(float4*)&C[(size_t)m * Vv + n] = v;
    }
  }
}

__global__ void k_zero(unsigned* __restrict__ f) { f[blockIdx.x * 256 + threadIdx.x] = 0u; }

// ---------------- fast grid barrier ----------------------------------------------------
// 64 cacheline-padded group counters, 4 blocks/group. Arrival: one release-add to the
// block's group line (4-way RMW contention instead of 256-way on a single line).
// Detection: wave 0, one counter per lane, relaxed load + __all ballot. Counters are
// monotonic (value == 4*bar when barrier `bar` complete), so no reuse/wrap hazard; a
// fast block racing ahead only makes its group counter larger. AGENT-scope
// release/acquire keeps the cross-XCD writeback/invalidate semantics of the proven
// single-counter barrier (G16).
__device__ __forceinline__ void gbar(unsigned* __restrict__ gc, unsigned bar,
                                     int tid, int blk) {
  __syncthreads();   // drains all waves' vmem before the release-add
  if (tid == 0)
    __hip_atomic_fetch_add(gc + (size_t)(blk & (NGRP - 1)) * FSTR, 1u,
                           __ATOMIC_RELEASE, __HIP_MEMORY_SCOPE_AGENT);
  if (tid < 64) {
    unsigned tgt = bar * (NBLK / NGRP);
    while (!__all(__hip_atomic_load(gc + (size_t)tid * FSTR, __ATOMIC_RELAXED,
                                    __HIP_MEMORY_SCOPE_AGENT) >= tgt)) { }
    if (tid == 0)
      (void)__hip_atomic_load(gc, __ATOMIC_ACQUIRE, __HIP_MEMORY_SCOPE_AGENT);
  }
  __syncthreads();
}

// ---------------- persistent recurrence, custom barrier --------------------------------
// 256 blocks x 512 threads. Phase A: 8 cols/block over [r|z] (2048 cols);
// 8 waves k-split 128, LDS reduce. Phase B: 4 cols/block, hbar + fused update.
__global__ __launch_bounds__(512) void k_recur(float* __restrict__ hT,
                                               float* __restrict__ rh,
                                               float* __restrict__ pre_z,
                                               const float* __restrict__ AtT_r,
                                               const float* __restrict__ AtT_z,
                                               const float* __restrict__ AtT_b,
                                               const float* __restrict__ Wr,
                                               const float* __restrict__ Wz,
                                               const float* __restrict__ Wbar,
                                               const float* __restrict__ start,
                                               float* __restrict__ hidden,
                                               unsigned* __restrict__ gcnt) {
  __shared__ float red[8 * 8 * 64];    // 16 KB
  __shared__ float lt[4 * 65];
  int tid = threadIdx.x;
  int lane = tid & 63;
  int wv = __builtin_amdgcn_readfirstlane(tid >> 6);
  int blk = blockIdx.x;
  int rc = tid >> 6, rb = tid & 63;    // reduce-phase mapping (col, batch)
  unsigned bar = 0;

  {  // h0 = broadcast(start)
    int g = blk * 512 + tid;
    if (g < Hh * Bb) hT[g] = start[g >> 6];
  }
  gbar(gcnt, ++bar, tid, blk);

  for (int t = 0; t < Tt; ++t) {
    // ---------------- phase A: r,z preactivations ----------------
    {
      int n0 = blk * 8;                       // 0..2047 across [r|z]
      // prefetch reduce-phase operands: their HBM/L2 latency hides under the k-loop
      int rn = n0 + rc;
      float at_pre, h_pre = 0.f;
      if (blk < 128) {
        at_pre = AtT_r[(size_t)t * 65536 + rn * 64 + rb];
        h_pre  = hT[rn * 64 + rb];
      } else {
        at_pre = AtT_z[(size_t)t * 65536 + (rn - 1024) * 64 + rb];
      }
      int k0 = wv * 128;
      const float* Wsel = (blk < 128) ? Wr : Wz;
      int nb = (blk < 128) ? n0 : n0 - 1024;
      const float* hk = hT + k0 * 64 + lane;
      const float* wbase = Wsel + (size_t)nb * 1536 + 512 + k0;
      float acc[8];
#pragma unroll
      for (int c = 0; c < 8; ++c) acc[c] = 0.f;
#pragma unroll 8
      for (int kk = 0; kk < 128; ++kk) {
        float vh = hk[kk * 64];
#pragma unroll
        for (int c = 0; c < 8; ++c)
          acc[c] = fmaf(wbase[(size_t)c * 1536 + kk], vh, acc[c]);
      }
#pragma unroll
      for (int c = 0; c < 8; ++c) red[(wv * 8 + c) * 64 + lane] = acc[c];
      __syncthreads();
      {
        float s = 0.f;                        // 512 outputs, one per thread
#pragma unroll
        for (int w = 0; w < 8; ++w) s += red[(w * 8 + rc) * 64 + rb];
        int n = n0 + rc;
        s += at_pre;
        if (blk < 128) {
          float sg = 1.f / (1.f + __expf(-s));
          rh[n * 64 + rb] = sg * h_pre;
        } else {
          pre_z[(n - 1024) * 64 + rb] = s;
        }
      }
    }
    gbar(gcnt, ++bar, tid, blk);
    // ---------------- phase B: hbar + fused update ----------------
    {
      int n0 = blk * 4;                       // 0..1023
      float at_pre = 0.f, pz_pre = 0.f, ho_pre = 0.f;
      if (tid < 256) {
        int n = n0 + rc;
        at_pre = AtT_b[(size_t)t * 65536 + n * 64 + rb];
        pz_pre = pre_z[n * 64 + rb];
        ho_pre = hT[n * 64 + rb];
      }
      int k0 = wv * 128;
      const float* hk = rh + k0 * 64 + lane;
      const float* wbase = Wbar + (size_t)n0 * 1536 + 512 + k0;
      float acc[4];
#pragma unroll
      for (int c = 0; c < 4; ++c) acc[c] = 0.f;
#pragma unroll 8
      for (int kk = 0; kk < 128; ++kk) {
        float vh = hk[kk * 64];
#pragma unroll
        for (int c = 0; c < 4; ++c)
          acc[c] = fmaf(wbase[(size_t)c * 1536 + kk], vh, acc[c]);
      }
#pragma unroll
      for (int c = 0; c < 4; ++c) red[(wv * 4 + c) * 64 + lane] = acc[c];
      __syncthreads();
      if (tid < 256) {
        float s = 0.f;
#pragma unroll
        for (int w = 0; w < 8; ++w) s += red[(w * 4 + rc) * 64 + rb];
        int n = n0 + rc;
        s += at_pre;
        float e = __expf(2.f * s);
        float hbt = 1.f - 2.f / (e + 1.f);    // tanh, saturation-safe
        float z = 1.f / (1.f + __expf(-pz_pre));
        float hn = ho_pre + z * (hbt - ho_pre);
        hT[n * 64 + rb] = hn;
        lt[rc * 65 + rb] = hn;
      }
      __syncthreads();
      if (tid < 64) {
        int b = tid;
        float4 v;
        v.x = lt[0 * 65 + b]; v.y = lt[1 * 65 + b];
        v.z = lt[2 * 65 + b]; v.w = lt[3 * 65 + b];
        *(float4*)&hidden[(size_t)b * (Tt * Hh) + (size_t)t * Hh + n0] = v;
      }
    }
    gbar(gcnt, ++bar, tid, blk);
  }
}

extern "C" void kernel_launch(void* const* d_in, const int* in_sizes, int n_in,
                              void* d_out, int out_size, void* d_ws, size_t ws_size,
                              hipStream_t stream) {
  (void)in_sizes; (void)n_in; (void)out_size; (void)ws_size;
  const int*   x     = (const int*)  d_in[0];
  const float* start = (const float*)d_in[1];
  const float* wte   = (const float*)d_in[2];
  const float* Wr    = (const float*)d_in[3];
  const float* br    = (const float*)d_in[4];
  const float* Wbar  = (const float*)d_in[5];
  const float* bbar  = (const float*)d_in[6];
  const float* Wz    = (const float*)d_in[7];
  const float* bz    = (const float*)d_in[8];
  const float* Whead = (const float*)d_in[9];
  const float* bhead = (const float*)d_in[10];
  float* out = (float*)d_out;

  float* p = (float*)d_ws;
  float* AtT_r  = p; p += (size_t)Tt * Hh * Bb;
  float* AtT_z  = p; p += (size_t)Tt * Hh * Bb;
  float* AtT_b  = p; p += (size_t)Tt * Hh * Bb;
  float* hidden = p; p += (size_t)Bb * Tt * Hh;
  float* hT     = p; p += Hh * Bb;
  float* rh     = p; p += Hh * Bb;
  float* pre_z  = p; p += Hh * Bb;
  unsigned* gcnt = (unsigned*)p;   // NGRP * FSTR = 1024 u32 (4 KB), line-padded flags

  dim3 b256(256);
  k_zero<<<dim3((NGRP * FSTR) / 256), b256, 0, stream>>>(gcnt);
  k_proj<<<dim3(128, 8), b256, 0, stream>>>(x, wte, Wr,   br,   AtT_r);
  k_proj<<<dim3(128, 8), b256, 0, stream>>>(x, wte, Wz,   bz,   AtT_z);
  k_proj<<<dim3(128, 8), b256, 0, stream>>>(x, wte, Wbar, bbar, AtT_b);

  void* args[] = {&hT, &rh, &pre_z, &AtT_r, &AtT_z, &AtT_b,
                  (void*)&Wr, (void*)&Wz, (void*)&Wbar, (void*)&start, &hidden, &gcnt};
  hipLaunchCooperativeKernel((void*)k_recur, dim3(NBLK), dim3(512), args, 0, stream);

  k_head<<<dim3(128, 32), b256, 0, stream>>>(hidden, Whead, bhead, out);
}

// Round 2
// 10342.947 us; speedup vs baseline: 1.3943x; 1.0835x over previous
//
#include <hip/hip_runtime.h>
#include <math.h>

#define Bb 64
#define Tt 256
#define Vv 4096
#define Ee 512
#define Hh 1024
#define NBLK 256
#define NGRP 64
#define FSTR 32   // one flag per 128B line
#define NWV 16    // waves per block in k_recur

// ---------------- input projection: AtT[t][n][b] = sum_e wte[x[b,t]][e]*W[n][e] + bias[n]
__global__ __launch_bounds__(256) void k_proj(const int* __restrict__ x,
                                              const float* __restrict__ wte,
                                              const float* __restrict__ W,
                                              const float* __restrict__ bias,
                                              float* __restrict__ AtT) {
  __shared__ float As[16][132];
  __shared__ float Bs[16][132];
  int tid = threadIdx.x;
  int m0 = blockIdx.x * 128;
  int n0 = blockIdx.y * 128;
  int tm = tid & 15, tn = tid >> 4;
  float acc[8][8];
#pragma unroll
  for (int i = 0; i < 8; ++i)
#pragma unroll
    for (int j = 0; j < 8; ++j) acc[i][j] = 0.f;

  for (int k0 = 0; k0 < Ee; k0 += 16) {
#pragma unroll
    for (int p = 0; p < 2; ++p) {
      int id = tid + p * 256;
      int row = id >> 2, c4 = id & 3;
      int m = m0 + row;
      int tok = x[(m & 63) * Tt + (m >> 6)];
      float4 v = *(const float4*)(wte + tok * Ee + k0 + c4 * 4);
      As[c4 * 4 + 0][row] = v.x; As[c4 * 4 + 1][row] = v.y;
      As[c4 * 4 + 2][row] = v.z; As[c4 * 4 + 3][row] = v.w;
    }
#pragma unroll
    for (int p = 0; p < 2; ++p) {
      int id = tid + p * 256;
      int row = id >> 2, c4 = id & 3;
      float4 v = *(const float4*)(W + (n0 + row) * 1536 + k0 + c4 * 4);
      Bs[c4 * 4 + 0][row] = v.x; Bs[c4 * 4 + 1][row] = v.y;
      Bs[c4 * 4 + 2][row] = v.z; Bs[c4 * 4 + 3][row] = v.w;
    }
    __syncthreads();
#pragma unroll
    for (int kk = 0; kk < 16; ++kk) {
      float4 a0 = *(const float4*)&As[kk][tm * 8];
      float4 a1 = *(const float4*)&As[kk][tm * 8 + 4];
      float4 b0 = *(const float4*)&Bs[kk][tn * 8];
      float4 b1 = *(const float4*)&Bs[kk][tn * 8 + 4];
      float av[8] = {a0.x, a0.y, a0.z, a0.w, a1.x, a1.y, a1.z, a1.w};
      float bv[8] = {b0.x, b0.y, b0.z, b0.w, b1.x, b1.y, b1.z, b1.w};
#pragma unroll
      for (int i = 0; i < 8; ++i)
#pragma unroll
        for (int j = 0; j < 8; ++j)
          acc[i][j] = fmaf(av[i], bv[j], acc[i][j]);
    }
    __syncthreads();
  }
#pragma unroll
  for (int i = 0; i < 8; ++i) {
    int m = m0 + tm * 8 + i;
    int t = m >> 6, b = m & 63;
#pragma unroll
    for (int j = 0; j < 8; ++j) {
      int n = n0 + tn * 8 + j;
      AtT[(size_t)t * (Hh * Bb) + n * Bb + b] = acc[i][j] + bias[n];
    }
  }
}

// ---------------- head GEMM ------------------------------------------------------------
__global__ __launch_bounds__(256) void k_head(const float* __restrict__ A,
                                              const float* __restrict__ W,
                                              const float* __restrict__ bias,
                                              float* __restrict__ C) {
  __shared__ float As[16][132];
  __shared__ float Bs[16][132];
  int tid = threadIdx.x;
  int m0 = blockIdx.x * 128;
  int n0 = blockIdx.y * 128;
  int tm = tid & 15, tn = tid >> 4;
  float acc[8][8];
#pragma unroll
  for (int i = 0; i < 8; ++i)
#pragma unroll
    for (int j = 0; j < 8; ++j) acc[i][j] = 0.f;

  for (int k0 = 0; k0 < Hh; k0 += 16) {
#pragma unroll
    for (int p = 0; p < 2; ++p) {
      int id = tid + p * 256;
      int row = id >> 2, c4 = id & 3;
      float4 v = *(const float4*)(A + (size_t)(m0 + row) * Hh + k0 + c4 * 4);
      As[c4 * 4 + 0][row] = v.x; As[c4 * 4 + 1][row] = v.y;
      As[c4 * 4 + 2][row] = v.z; As[c4 * 4 + 3][row] = v.w;
    }
#pragma unroll
    for (int p = 0; p < 2; ++p) {
      int id = tid + p * 256;
      int row = id >> 2, c4 = id & 3;
      float4 v = *(const float4*)(W + (size_t)(n0 + row) * Hh + k0 + c4 * 4);
      Bs[c4 * 4 + 0][row] = v.x; Bs[c4 * 4 + 1][row] = v.y;
      Bs[c4 * 4 + 2][row] = v.z; Bs[c4 * 4 + 3][row] = v.w;
    }
    __syncthreads();
#pragma unroll
    for (int kk = 0; kk < 16; ++kk) {
      float4 a0 = *(const float4*)&As[kk][tm * 8];
      float4 a1 = *(const float4*)&As[kk][tm * 8 + 4];
      float4 b0 = *(const float4*)&Bs[kk][tn * 8];
      float4 b1 = *(const float4*)&Bs[kk][tn * 8 + 4];
      float av[8] = {a0.x, a0.y, a0.z, a0.w, a1.x, a1.y, a1.z, a1.w};
      float bv[8] = {b0.x, b0.y, b0.z, b0.w, b1.x, b1.y, b1.z, b1.w};
#pragma unroll
      for (int i = 0; i < 8; ++i)
#pragma unroll
        for (int j = 0; j < 8; ++j)
          acc[i][j] = fmaf(av[i], bv[j], acc[i][j]);
    }
    __syncthreads();
  }
#pragma unroll
  for (int i = 0; i < 8; ++i) {
    int m = m0 + tm * 8 + i;
#pragma unroll
    for (int jj = 0; jj < 2; ++jj) {
      int n = n0 + tn * 8 + jj * 4;
      float4 v;
      v.x = acc[i][jj * 4 + 0] + bias[n + 0];
      v.y = acc[i][jj * 4 + 1] + bias[n + 1];
      v.z = acc[i][jj * 4 + 2] + bias[n + 2];
      v.w = acc[i][jj * 4 + 3] + bias[n + 3];
      *(float4*)&C[(size_t)m * Vv + n] = v;
    }
  }
}

__global__ void k_zero(unsigned* __restrict__ f) {
  int g = blockIdx.x * 256 + threadIdx.x;
  if (g < NGRP * FSTR + FSTR) f[g] = 0u;
}

// ---------------- two-hop master grid barrier ------------------------------------------
// Arrival: one release-add per block to its group line (4-way RMW contention).
// Detection: ONLY block 0 polls the 64 group counters (one lane each); it then
// publishes a monotonic epoch flag (single read-shared line) that all other blocks
// spin on with a single lane. Spin traffic drops from 16K lanes x 64 lines to
// 64 lanes + 255 lanes x 1 line. HB chain: release-add -> per-lane acquire loads in
// master -> __syncthreads (block-scope fence) -> release flag store -> waiter acquire.
// All counters/flag are monotonic: no reuse/wrap hazard. AGENT scope keeps the
// cross-XCD writeback/invalidate semantics of the proven barrier (G16).
__device__ __forceinline__ void gbar(unsigned* __restrict__ gc, unsigned bar,
                                     int tid, int blk) {
  unsigned* flag = gc + (size_t)NGRP * FSTR;
  __syncthreads();   // drains all waves' vmem before the release-add
  if (tid == 0)
    __hip_atomic_fetch_add(gc + (size_t)(blk & (NGRP - 1)) * FSTR, 1u,
                           __ATOMIC_RELEASE, __HIP_MEMORY_SCOPE_AGENT);
  if (blk == 0) {
    if (tid < NGRP) {
      unsigned tgt = bar * (NBLK / NGRP);
      while (!__all(__hip_atomic_load(gc + (size_t)tid * FSTR, __ATOMIC_RELAXED,
                                      __HIP_MEMORY_SCOPE_AGENT) >= tgt)) { }
      (void)__hip_atomic_load(gc + (size_t)tid * FSTR, __ATOMIC_ACQUIRE,
                              __HIP_MEMORY_SCOPE_AGENT);
    }
    __syncthreads();             // orders the 64 lanes' acquires before the flag store
    if (tid == 0)
      __hip_atomic_store(flag, bar, __ATOMIC_RELEASE, __HIP_MEMORY_SCOPE_AGENT);
  } else if (tid == 0) {
    while (__hip_atomic_load(flag, __ATOMIC_RELAXED, __HIP_MEMORY_SCOPE_AGENT) < bar) { }
    (void)__hip_atomic_load(flag, __ATOMIC_ACQUIRE, __HIP_MEMORY_SCOPE_AGENT);
  }
  __syncthreads();
}

// ---------------- persistent recurrence ------------------------------------------------
// 256 blocks x 1024 threads (16 waves -> 4/SIMD for latency hiding).
// Phase A: 8 cols/block over [r|z] (2048 cols); 16 waves k-split 64, LDS reduce.
// Phase B: 4 cols/block, hbar + fused update.
__global__ __launch_bounds__(1024) void k_recur(float* __restrict__ hT,
                                                float* __restrict__ rh,
                                                float* __restrict__ pre_z,
                                                const float* __restrict__ AtT_r,
                                                const float* __restrict__ AtT_z,
                                                const float* __restrict__ AtT_b,
                                                const float* __restrict__ Wr,
                                                const float* __restrict__ Wz,
                                                const float* __restrict__ Wbar,
                                                const float* __restrict__ start,
                                                float* __restrict__ hidden,
                                                unsigned* __restrict__ gcnt) {
  __shared__ float red[NWV * 8 * 64];    // 32 KB
  __shared__ float lt[4 * 65];
  int tid = threadIdx.x;
  int lane = tid & 63;
  int wv = __builtin_amdgcn_readfirstlane(tid >> 6);
  int blk = blockIdx.x;
  int rc = tid >> 6, rb = tid & 63;      // reduce-phase mapping (col, batch)
  unsigned bar = 0;

  {  // h0 = broadcast(start)
    int g = blk * 1024 + tid;
    if (g < Hh * Bb) hT[g] = start[g >> 6];
  }
  gbar(gcnt, ++bar, tid, blk);

  for (int t = 0; t < Tt; ++t) {
    // ---------------- phase A: r,z preactivations ----------------
    {
      int n0 = blk * 8;                       // 0..2047 across [r|z]
      // prefetch reduce-phase operands: their HBM/L2 latency hides under the k-loop
      float at_pre = 0.f, h_pre = 0.f;
      if (tid < 512) {
        int rn = n0 + rc;
        if (blk < 128) {
          at_pre = AtT_r[(size_t)t * 65536 + rn * 64 + rb];
          h_pre  = hT[rn * 64 + rb];
        } else {
          at_pre = AtT_z[(size_t)t * 65536 + (rn - 1024) * 64 + rb];
        }
      }
      int k0 = wv * 64;
      const float* Wsel = (blk < 128) ? Wr : Wz;
      int nb = (blk < 128) ? n0 : n0 - 1024;
      const float* hk = hT + k0 * 64 + lane;
      const float* wbase = Wsel + (size_t)nb * 1536 + 512 + k0;
      float acc[8];
#pragma unroll
      for (int c = 0; c < 8; ++c) acc[c] = 0.f;
#pragma unroll 8
      for (int kk = 0; kk < 64; ++kk) {
        float vh = hk[kk * 64];
#pragma unroll
        for (int c = 0; c < 8; ++c)
          acc[c] = fmaf(wbase[(size_t)c * 1536 + kk], vh, acc[c]);
      }
#pragma unroll
      for (int c = 0; c < 8; ++c) red[(wv * 8 + c) * 64 + lane] = acc[c];
      __syncthreads();
      if (tid < 512) {
        float s = 0.f;                        // 512 outputs, one per thread
#pragma unroll
        for (int w = 0; w < NWV; ++w) s += red[(w * 8 + rc) * 64 + rb];
        int n = n0 + rc;
        s += at_pre;
        if (blk < 128) {
          float sg = 1.f / (1.f + __expf(-s));
          rh[n * 64 + rb] = sg * h_pre;
        } else {
          pre_z[(n - 1024) * 64 + rb] = s;
        }
      }
    }
    gbar(gcnt, ++bar, tid, blk);
    // ---------------- phase B: hbar + fused update ----------------
    {
      int n0 = blk * 4;                       // 0..1023
      float at_pre = 0.f, pz_pre = 0.f, ho_pre = 0.f;
      if (tid < 256) {
        int n = n0 + rc;
        at_pre = AtT_b[(size_t)t * 65536 + n * 64 + rb];
        pz_pre = pre_z[n * 64 + rb];
        ho_pre = hT[n * 64 + rb];
      }
      int k0 = wv * 64;
      const float* hk = rh + k0 * 64 + lane;
      const float* wbase = Wbar + (size_t)n0 * 1536 + 512 + k0;
      float acc[4];
#pragma unroll
      for (int c = 0; c < 4; ++c) acc[c] = 0.f;
#pragma unroll 8
      for (int kk = 0; kk < 64; ++kk) {
        float vh = hk[kk * 64];
#pragma unroll
        for (int c = 0; c < 4; ++c)
          acc[c] = fmaf(wbase[(size_t)c * 1536 + kk], vh, acc[c]);
      }
#pragma unroll
      for (int c = 0; c < 4; ++c) red[(wv * 4 + c) * 64 + lane] = acc[c];
      __syncthreads();
      if (tid < 256) {
        float s = 0.f;
#pragma unroll
        for (int w = 0; w < NWV; ++w) s += red[(w * 4 + rc) * 64 + rb];
        int n = n0 + rc;
        s += at_pre;
        float e = __expf(2.f * s);
        float hbt = 1.f - 2.f / (e + 1.f);    // tanh, saturation-safe
        float z = 1.f / (1.f + __expf(-pz_pre));
        float hn = ho_pre + z * (hbt - ho_pre);
        hT[n * 64 + rb] = hn;
        lt[rc * 65 + rb] = hn;
      }
      __syncthreads();
      if (tid < 64) {
        int b = tid;
        float4 v;
        v.x = lt[0 * 65 + b]; v.y = lt[1 * 65 + b];
        v.z = lt[2 * 65 + b]; v.w = lt[3 * 65 + b];
        *(float4*)&hidden[(size_t)b * (Tt * Hh) + (size_t)t * Hh + n0] = v;
      }
    }
    gbar(gcnt, ++bar, tid, blk);
  }
}

extern "C" void kernel_launch(void* const* d_in, const int* in_sizes, int n_in,
                              void* d_out, int out_size, void* d_ws, size_t ws_size,
                              hipStream_t stream) {
  (void)in_sizes; (void)n_in; (void)out_size; (void)ws_size;
  const int*   x     = (const int*)  d_in[0];
  const float* start = (const float*)d_in[1];
  const float* wte   = (const float*)d_in[2];
  const float* Wr    = (const float*)d_in[3];
  const float* br    = (const float*)d_in[4];
  const float* Wbar  = (const float*)d_in[5];
  const float* bbar  = (const float*)d_in[6];
  const float* Wz    = (const float*)d_in[7];
  const float* bz    = (const float*)d_in[8];
  const float* Whead = (const float*)d_in[9];
  const float* bhead = (const float*)d_in[10];
  float* out = (float*)d_out;

  float* p = (float*)d_ws;
  float* AtT_r  = p; p += (size_t)Tt * Hh * Bb;
  float* AtT_z  = p; p += (size_t)Tt * Hh * Bb;
  float* AtT_b  = p; p += (size_t)Tt * Hh * Bb;
  float* hidden = p; p += (size_t)Bb * Tt * Hh;
  float* hT     = p; p += Hh * Bb;
  float* rh     = p; p += Hh * Bb;
  float* pre_z  = p; p += Hh * Bb;
  unsigned* gcnt = (unsigned*)p;   // NGRP*FSTR counters + 1 epoch flag line

  dim3 b256(256);
  k_zero<<<dim3((NGRP * FSTR + FSTR + 255) / 256), b256, 0, stream>>>(gcnt);
  k_proj<<<dim3(128, 8), b256, 0, stream>>>(x, wte, Wr,   br,   AtT_r);
  k_proj<<<dim3(128, 8), b256, 0, stream>>>(x, wte, Wz,   bz,   AtT_z);
  k_proj<<<dim3(128, 8), b256, 0, stream>>>(x, wte, Wbar, bbar, AtT_b);

  void* args[] = {&hT, &rh, &pre_z, &AtT_r, &AtT_z, &AtT_b,
                  (void*)&Wr, (void*)&Wz, (void*)&Wbar, (void*)&start, &hidden, &gcnt};
  hipLaunchCooperativeKernel((void*)k_recur, dim3(NBLK), dim3(1024), args, 0, stream);

  k_head<<<dim3(128, 32), b256, 0, stream>>>(hidden, Whead, bhead, out);
}

// Round 3
// 5611.044 us; speedup vs baseline: 2.5701x; 1.8433x over previous
//
#include <hip/hip_runtime.h>
#include <math.h>

#define Bb 64
#define Tt 256
#define Vv 4096
#define Ee 512
#define Hh 1024
#define NBLK 256
#define NGRP 64
#define FSTR 32   // one flag per 128B line
#define NWV 16    // waves per block in k_recur

// LLC-coherent (cross-XCD) access without cache-maintenance fences:
// relaxed AGENT-scope atomics lower to global_load/store with sc0|sc1 —
// they read/write the coherence point (LLC) and never leave stale-able
// L2 copies. No buffer_inv / buffer_wbl2 is emitted (those come only from
// acquire/release), so per-XCD L2s keep read-only data (weights) hot.
#define DEV_LOAD(p)     __hip_atomic_load((p), __ATOMIC_RELAXED, __HIP_MEMORY_SCOPE_AGENT)
#define DEV_STORE(p, v) __hip_atomic_store((p), (v), __ATOMIC_RELAXED, __HIP_MEMORY_SCOPE_AGENT)

// ---------------- input projection: AtT[t][n][b] = sum_e wte[x[b,t]][e]*W[n][e] + bias[n]
__global__ __launch_bounds__(256) void k_proj(const int* __restrict__ x,
                                              const float* __restrict__ wte,
                                              const float* __restrict__ W,
                                              const float* __restrict__ bias,
                                              float* __restrict__ AtT) {
  __shared__ float As[16][132];
  __shared__ float Bs[16][132];
  int tid = threadIdx.x;
  int m0 = blockIdx.x * 128;
  int n0 = blockIdx.y * 128;
  int tm = tid & 15, tn = tid >> 4;
  float acc[8][8];
#pragma unroll
  for (int i = 0; i < 8; ++i)
#pragma unroll
    for (int j = 0; j < 8; ++j) acc[i][j] = 0.f;

  for (int k0 = 0; k0 < Ee; k0 += 16) {
#pragma unroll
    for (int p = 0; p < 2; ++p) {
      int id = tid + p * 256;
      int row = id >> 2, c4 = id & 3;
      int m = m0 + row;
      int tok = x[(m & 63) * Tt + (m >> 6)];
      float4 v = *(const float4*)(wte + tok * Ee + k0 + c4 * 4);
      As[c4 * 4 + 0][row] = v.x; As[c4 * 4 + 1][row] = v.y;
      As[c4 * 4 + 2][row] = v.z; As[c4 * 4 + 3][row] = v.w;
    }
#pragma unroll
    for (int p = 0; p < 2; ++p) {
      int id = tid + p * 256;
      int row = id >> 2, c4 = id & 3;
      float4 v = *(const float4*)(W + (n0 + row) * 1536 + k0 + c4 * 4);
      Bs[c4 * 4 + 0][row] = v.x; Bs[c4 * 4 + 1][row] = v.y;
      Bs[c4 * 4 + 2][row] = v.z; Bs[c4 * 4 + 3][row] = v.w;
    }
    __syncthreads();
#pragma unroll
    for (int kk = 0; kk < 16; ++kk) {
      float4 a0 = *(const float4*)&As[kk][tm * 8];
      float4 a1 = *(const float4*)&As[kk][tm * 8 + 4];
      float4 b0 = *(const float4*)&Bs[kk][tn * 8];
      float4 b1 = *(const float4*)&Bs[kk][tn * 8 + 4];
      float av[8] = {a0.x, a0.y, a0.z, a0.w, a1.x, a1.y, a1.z, a1.w};
      float bv[8] = {b0.x, b0.y, b0.z, b0.w, b1.x, b1.y, b1.z, b1.w};
#pragma unroll
      for (int i = 0; i < 8; ++i)
#pragma unroll
        for (int j = 0; j < 8; ++j)
          acc[i][j] = fmaf(av[i], bv[j], acc[i][j]);
    }
    __syncthreads();
  }
#pragma unroll
  for (int i = 0; i < 8; ++i) {
    int m = m0 + tm * 8 + i;
    int t = m >> 6, b = m & 63;
#pragma unroll
    for (int j = 0; j < 8; ++j) {
      int n = n0 + tn * 8 + j;
      AtT[(size_t)t * (Hh * Bb) + n * Bb + b] = acc[i][j] + bias[n];
    }
  }
}

// ---------------- head GEMM: A is ht1[t][n][b] (t-major slices of [1024][64]) ----------
// out[(b*Tt+t)*Vv + v] = sum_n ht1[t][n][b] * Whead[v][n] + bhead[v]
// m-index = t*64 + b; a 128-row m-tile = 2 consecutive t-slices x all 64 b.
__global__ __launch_bounds__(256) void k_head(const float* __restrict__ A,
                                              const float* __restrict__ W,
                                              const float* __restrict__ bias,
                                              float* __restrict__ C) {
  __shared__ float As[16][132];
  __shared__ float Bs[16][132];
  int tid = threadIdx.x;
  int m0 = blockIdx.x * 128;
  int n0 = blockIdx.y * 128;
  int tm = tid & 15, tn = tid >> 4;
  float acc[8][8];
#pragma unroll
  for (int i = 0; i < 8; ++i)
#pragma unroll
    for (int j = 0; j < 8; ++j) acc[i][j] = 0.f;

  for (int k0 = 0; k0 < Hh; k0 += 16) {
    // A-tile: As[k][row], row = rg*4..rg*4+3 are 4 consecutive b at one t
#pragma unroll
    for (int p = 0; p < 2; ++p) {
      int id = tid + p * 256;            // 0..511
      int kk = id & 15;                  // k offset
      int rg = id >> 4;                  // 0..31 row-group
      int row = rg * 4;
      int t = (m0 + row) >> 6;
      int b0 = (rg & 15) * 4;
      float4 v = *(const float4*)(A + (size_t)t * (Hh * Bb) + (k0 + kk) * Bb + b0);
      As[kk][row + 0] = v.x; As[kk][row + 1] = v.y;
      As[kk][row + 2] = v.z; As[kk][row + 3] = v.w;
    }
#pragma unroll
    for (int p = 0; p < 2; ++p) {
      int id = tid + p * 256;
      int row = id >> 2, c4 = id & 3;
      float4 v = *(const float4*)(W + (size_t)(n0 + row) * Hh + k0 + c4 * 4);
      Bs[c4 * 4 + 0][row] = v.x; Bs[c4 * 4 + 1][row] = v.y;
      Bs[c4 * 4 + 2][row] = v.z; Bs[c4 * 4 + 3][row] = v.w;
    }
    __syncthreads();
#pragma unroll
    for (int kk = 0; kk < 16; ++kk) {
      float4 a0 = *(const float4*)&As[kk][tm * 8];
      float4 a1 = *(const float4*)&As[kk][tm * 8 + 4];
      float4 b0 = *(const float4*)&Bs[kk][tn * 8];
      float4 b1 = *(const float4*)&Bs[kk][tn * 8 + 4];
      float av[8] = {a0.x, a0.y, a0.z, a0.w, a1.x, a1.y, a1.z, a1.w};
      float bv[8] = {b0.x, b0.y, b0.z, b0.w, b1.x, b1.y, b1.z, b1.w};
#pragma unroll
      for (int i = 0; i < 8; ++i)
#pragma unroll
        for (int j = 0; j < 8; ++j)
          acc[i][j] = fmaf(av[i], bv[j], acc[i][j]);
    }
    __syncthreads();
  }
#pragma unroll
  for (int i = 0; i < 8; ++i) {
    int m = m0 + tm * 8 + i;
    int t = m >> 6, b = m & 63;
    size_t rowo = (size_t)(b * Tt + t) * Vv;
#pragma unroll
    for (int jj = 0; jj < 2; ++jj) {
      int n = n0 + tn * 8 + jj * 4;
      float4 v;
      v.x = acc[i][jj * 4 + 0] + bias[n + 0];
      v.y = acc[i][jj * 4 + 1] + bias[n + 1];
      v.z = acc[i][jj * 4 + 2] + bias[n + 2];
      v.w = acc[i][jj * 4 + 3] + bias[n + 3];
      *(float4*)&C[rowo + n] = v;
    }
  }
}

__global__ void k_zero(unsigned* __restrict__ f) {
  int g = blockIdx.x * 256 + threadIdx.x;
  if (g < NGRP * FSTR + FSTR) f[g] = 0u;
}

// ---------------- relaxed-only two-hop grid barrier ------------------------------------
// NO acquire/release fences -> no buffer_wbl2 / buffer_inv (no L2 nukes).
// Correctness: all cross-block data is written with sc0|sc1 stores (DEV_STORE), which
// complete at the LLC; the __syncthreads() entering gbar drains vmcnt(0), so the
// relaxed arrival-add reaches the LLC strictly after the data. Master observes all
// group counters, publishes the epoch flag; waiters observe the flag and only then
// issue their reads, which are either sc0|sc1 (LLC read-through) or normal loads of
// never-before-touched addresses (fresh h slices) -> no stale cache line can exist.
__device__ __forceinline__ void gbar(unsigned* __restrict__ gc, unsigned bar,
                                     int tid, int blk) {
  unsigned* flag = gc + (size_t)NGRP * FSTR;
  __syncthreads();   // drains vmcnt(0): all sc1 data stores committed at LLC
  if (tid == 0)
    __hip_atomic_fetch_add(gc + (size_t)(blk & (NGRP - 1)) * FSTR, 1u,
                           __ATOMIC_RELAXED, __HIP_MEMORY_SCOPE_AGENT);
  if (blk == 0) {
    if (tid < NGRP) {
      unsigned tgt = bar * (NBLK / NGRP);
      while (!__all(__hip_atomic_load(gc + (size_t)tid * FSTR, __ATOMIC_RELAXED,
                                      __HIP_MEMORY_SCOPE_AGENT) >= tgt)) { }
    }
    __syncthreads();             // all 64 observations precede the flag store
    if (tid == 0)
      __hip_atomic_store(flag, bar, __ATOMIC_RELAXED, __HIP_MEMORY_SCOPE_AGENT);
  } else if (tid == 0) {
    while (__hip_atomic_load(flag, __ATOMIC_RELAXED, __HIP_MEMORY_SCOPE_AGENT) < bar) { }
  }
  __asm__ __volatile__("" ::: "memory");  // no load hoisting above the spin
  __syncthreads();
}

// ---------------- persistent recurrence ------------------------------------------------
// 256 blocks x 1024 threads. ht_all[t][n][b]: slice 0 = h0, slice t+1 written by step t
// (write-once addresses -> normal cached reads are safe). rh/pre_z: sc1-only access.
__global__ __launch_bounds__(1024) void k_recur(float* __restrict__ ht_all,
                                                float* __restrict__ rh,
                                                float* __restrict__ pre_z,
                                                const float* __restrict__ AtT_r,
                                                const float* __restrict__ AtT_z,
                                                const float* __restrict__ AtT_b,
                                                const float* __restrict__ Wr,
                                                const float* __restrict__ Wz,
                                                const float* __restrict__ Wbar,
                                                const float* __restrict__ start,
                                                unsigned* __restrict__ gcnt) {
  __shared__ float red[NWV * 8 * 64];    // 32 KB
  int tid = threadIdx.x;
  int lane = tid & 63;
  int wv = __builtin_amdgcn_readfirstlane(tid >> 6);
  int blk = blockIdx.x;
  int rc = tid >> 6, rb = tid & 63;      // reduce-phase mapping (col, batch)
  unsigned bar = 0;

  {  // slice 0 = broadcast(start), pushed to LLC
    int g = blk * 1024 + tid;
    if (g < Hh * Bb) DEV_STORE(ht_all + g, start[g >> 6]);
  }
  gbar(gcnt, ++bar, tid, blk);

  for (int t = 0; t < Tt; ++t) {
    const float* hcur = ht_all + (size_t)t * 65536;   // slice t: written once, cached ok
    // ---------------- phase A: r,z preactivations ----------------
    {
      int n0 = blk * 8;                       // 0..2047 across [r|z]
      float at_pre = 0.f, h_pre = 0.f;
      if (tid < 512) {
        int rn = n0 + rc;
        if (blk < 128) {
          at_pre = AtT_r[(size_t)t * 65536 + rn * 64 + rb];
          h_pre  = hcur[rn * 64 + rb];
        } else {
          at_pre = AtT_z[(size_t)t * 65536 + (rn - 1024) * 64 + rb];
        }
      }
      int k0 = wv * 64;
      const float* Wsel = (blk < 128) ? Wr : Wz;
      int nb = (blk < 128) ? n0 : n0 - 1024;
      const float* hk = hcur + k0 * 64 + lane;
      const float* wbase = Wsel + (size_t)nb * 1536 + 512 + k0;
      float acc[8];
#pragma unroll
      for (int c = 0; c < 8; ++c) acc[c] = 0.f;
#pragma unroll 8
      for (int kk = 0; kk < 64; ++kk) {
        float vh = hk[kk * 64];
#pragma unroll
        for (int c = 0; c < 8; ++c)
          acc[c] = fmaf(wbase[(size_t)c * 1536 + kk], vh, acc[c]);
      }
#pragma unroll
      for (int c = 0; c < 8; ++c) red[(wv * 8 + c) * 64 + lane] = acc[c];
      __syncthreads();
      if (tid < 512) {
        float s = 0.f;
#pragma unroll
        for (int w = 0; w < NWV; ++w) s += red[(w * 8 + rc) * 64 + rb];
        int n = n0 + rc;
        s += at_pre;
        if (blk < 128) {
          float sg = 1.f / (1.f + __expf(-s));
          DEV_STORE(rh + n * 64 + rb, sg * h_pre);
        } else {
          DEV_STORE(pre_z + (n - 1024) * 64 + rb, s);
        }
      }
    }
    gbar(gcnt, ++bar, tid, blk);
    // ---------------- phase B: hbar + fused update ----------------
    {
      int n0 = blk * 4;                       // 0..1023
      float at_pre = 0.f, pz_pre = 0.f, ho_pre = 0.f;
      if (tid < 256) {
        int n = n0 + rc;
        at_pre = AtT_b[(size_t)t * 65536 + n * 64 + rb];
        pz_pre = DEV_LOAD(pre_z + n * 64 + rb);
        ho_pre = hcur[n * 64 + rb];
      }
      int k0 = wv * 64;
      const float* hk = rh + k0 * 64 + lane;
      const float* wbase = Wbar + (size_t)n0 * 1536 + 512 + k0;
      float acc[4];
#pragma unroll
      for (int c = 0; c < 4; ++c) acc[c] = 0.f;
#pragma unroll 16
      for (int kk = 0; kk < 64; ++kk) {
        float vh = DEV_LOAD(hk + kk * 64);   // LLC read-through (address reused/step)
#pragma unroll
        for (int c = 0; c < 4; ++c)
          acc[c] = fmaf(wbase[(size_t)c * 1536 + kk], vh, acc[c]);
      }
#pragma unroll
      for (int c = 0; c < 4; ++c) red[(wv * 4 + c) * 64 + lane] = acc[c];
      __syncthreads();
      if (tid < 256) {
        float s = 0.f;
#pragma unroll
        for (int w = 0; w < NWV; ++w) s += red[(w * 4 + rc) * 64 + rb];
        int n = n0 + rc;
        s += at_pre;
        float e = __expf(2.f * s);
        float hbt = 1.f - 2.f / (e + 1.f);    // tanh, saturation-safe
        float z = 1.f / (1.f + __expf(-pz_pre));
        float hn = ho_pre + z * (hbt - ho_pre);
        DEV_STORE(ht_all + (size_t)(t + 1) * 65536 + n * 64 + rb, hn);
      }
    }
    gbar(gcnt, ++bar, tid, blk);
  }
}

extern "C" void kernel_launch(void* const* d_in, const int* in_sizes, int n_in,
                              void* d_out, int out_size, void* d_ws, size_t ws_size,
                              hipStream_t stream) {
  (void)in_sizes; (void)n_in; (void)out_size; (void)ws_size;
  const int*   x     = (const int*)  d_in[0];
  const float* start = (const float*)d_in[1];
  const float* wte   = (const float*)d_in[2];
  const float* Wr    = (const float*)d_in[3];
  const float* br    = (const float*)d_in[4];
  const float* Wbar  = (const float*)d_in[5];
  const float* bbar  = (const float*)d_in[6];
  const float* Wz    = (const float*)d_in[7];
  const float* bz    = (const float*)d_in[8];
  const float* Whead = (const float*)d_in[9];
  const float* bhead = (const float*)d_in[10];
  float* out = (float*)d_out;

  float* p = (float*)d_ws;
  float* AtT_r  = p; p += (size_t)Tt * Hh * Bb;
  float* AtT_z  = p; p += (size_t)Tt * Hh * Bb;
  float* AtT_b  = p; p += (size_t)Tt * Hh * Bb;
  float* ht_all = p; p += (size_t)(Tt + 1) * Hh * Bb;   // slice 0 = h0; slices 1..T = hidden
  float* rh     = p; p += Hh * Bb;
  float* pre_z  = p; p += Hh * Bb;
  unsigned* gcnt = (unsigned*)p;   // NGRP*FSTR counters + 1 epoch flag line

  dim3 b256(256);
  k_zero<<<dim3((NGRP * FSTR + FSTR + 255) / 256), b256, 0, stream>>>(gcnt);
  k_proj<<<dim3(128, 8), b256, 0, stream>>>(x, wte, Wr,   br,   AtT_r);
  k_proj<<<dim3(128, 8), b256, 0, stream>>>(x, wte, Wz,   bz,   AtT_z);
  k_proj<<<dim3(128, 8), b256, 0, stream>>>(x, wte, Wbar, bbar, AtT_b);

  void* args[] = {&ht_all, &rh, &pre_z, &AtT_r, &AtT_z, &AtT_b,
                  (void*)&Wr, (void*)&Wz, (void*)&Wbar, (void*)&start, &gcnt};
  hipLaunchCooperativeKernel((void*)k_recur, dim3(NBLK), dim3(1024), args, 0, stream);

  k_head<<<dim3(128, 32), b256, 0, stream>>>(ht_all + Hh * Bb, Whead, bhead, out);
}

// Round 4
// 5385.933 us; speedup vs baseline: 2.6775x; 1.0418x over previous
//
#include <hip/hip_runtime.h>
#include <math.h>

#define Bb 64
#define Tt 256
#define Vv 4096
#define Ee 512
#define Hh 1024
#define NBLK 256
#define NGRP 64
#define FSTR 32   // one flag per 128B line
#define NWV 16    // waves per block in k_recur

// LLC-coherent (cross-XCD) access without cache-maintenance fences:
// relaxed AGENT-scope atomics lower to global_load/store with sc0|sc1 —
// they read/write the coherence point (LLC) and never leave stale-able
// L2 copies. No buffer_inv / buffer_wbl2 is emitted (those come only from
// acquire/release), so per-XCD L2s keep read-only data (weights) hot.
#define DEV_LOAD(p)     __hip_atomic_load((p), __ATOMIC_RELAXED, __HIP_MEMORY_SCOPE_AGENT)
#define DEV_STORE(p, v) __hip_atomic_store((p), (v), __ATOMIC_RELAXED, __HIP_MEMORY_SCOPE_AGENT)

// ---------------- input projection: AtT[t][n][b] = sum_e wte[x[b,t]][e]*W[n][e] + bias[n]
__global__ __launch_bounds__(256) void k_proj(const int* __restrict__ x,
                                              const float* __restrict__ wte,
                                              const float* __restrict__ W,
                                              const float* __restrict__ bias,
                                              float* __restrict__ AtT) {
  __shared__ float As[16][132];
  __shared__ float Bs[16][132];
  int tid = threadIdx.x;
  int m0 = blockIdx.x * 128;
  int n0 = blockIdx.y * 128;
  int tm = tid & 15, tn = tid >> 4;
  float acc[8][8];
#pragma unroll
  for (int i = 0; i < 8; ++i)
#pragma unroll
    for (int j = 0; j < 8; ++j) acc[i][j] = 0.f;

  for (int k0 = 0; k0 < Ee; k0 += 16) {
#pragma unroll
    for (int p = 0; p < 2; ++p) {
      int id = tid + p * 256;
      int row = id >> 2, c4 = id & 3;
      int m = m0 + row;
      int tok = x[(m & 63) * Tt + (m >> 6)];
      float4 v = *(const float4*)(wte + tok * Ee + k0 + c4 * 4);
      As[c4 * 4 + 0][row] = v.x; As[c4 * 4 + 1][row] = v.y;
      As[c4 * 4 + 2][row] = v.z; As[c4 * 4 + 3][row] = v.w;
    }
#pragma unroll
    for (int p = 0; p < 2; ++p) {
      int id = tid + p * 256;
      int row = id >> 2, c4 = id & 3;
      float4 v = *(const float4*)(W + (n0 + row) * 1536 + k0 + c4 * 4);
      Bs[c4 * 4 + 0][row] = v.x; Bs[c4 * 4 + 1][row] = v.y;
      Bs[c4 * 4 + 2][row] = v.z; Bs[c4 * 4 + 3][row] = v.w;
    }
    __syncthreads();
#pragma unroll
    for (int kk = 0; kk < 16; ++kk) {
      float4 a0 = *(const float4*)&As[kk][tm * 8];
      float4 a1 = *(const float4*)&As[kk][tm * 8 + 4];
      float4 b0 = *(const float4*)&Bs[kk][tn * 8];
      float4 b1 = *(const float4*)&Bs[kk][tn * 8 + 4];
      float av[8] = {a0.x, a0.y, a0.z, a0.w, a1.x, a1.y, a1.z, a1.w};
      float bv[8] = {b0.x, b0.y, b0.z, b0.w, b1.x, b1.y, b1.z, b1.w};
#pragma unroll
      for (int i = 0; i < 8; ++i)
#pragma unroll
        for (int j = 0; j < 8; ++j)
          acc[i][j] = fmaf(av[i], bv[j], acc[i][j]);
    }
    __syncthreads();
  }
#pragma unroll
  for (int i = 0; i < 8; ++i) {
    int m = m0 + tm * 8 + i;
    int t = m >> 6, b = m & 63;
#pragma unroll
    for (int j = 0; j < 8; ++j) {
      int n = n0 + tn * 8 + j;
      AtT[(size_t)t * (Hh * Bb) + n * Bb + b] = acc[i][j] + bias[n];
    }
  }
}

// ---------------- head GEMM: A is ht1[t][n][b] (t-major slices of [1024][64]) ----------
__global__ __launch_bounds__(256) void k_head(const float* __restrict__ A,
                                              const float* __restrict__ W,
                                              const float* __restrict__ bias,
                                              float* __restrict__ C) {
  __shared__ float As[16][132];
  __shared__ float Bs[16][132];
  int tid = threadIdx.x;
  int m0 = blockIdx.x * 128;
  int n0 = blockIdx.y * 128;
  int tm = tid & 15, tn = tid >> 4;
  float acc[8][8];
#pragma unroll
  for (int i = 0; i < 8; ++i)
#pragma unroll
    for (int j = 0; j < 8; ++j) acc[i][j] = 0.f;

  for (int k0 = 0; k0 < Hh; k0 += 16) {
#pragma unroll
    for (int p = 0; p < 2; ++p) {
      int id = tid + p * 256;            // 0..511
      int kk = id & 15;                  // k offset
      int rg = id >> 4;                  // 0..31 row-group
      int row = rg * 4;
      int t = (m0 + row) >> 6;
      int b0 = (rg & 15) * 4;
      float4 v = *(const float4*)(A + (size_t)t * (Hh * Bb) + (k0 + kk) * Bb + b0);
      As[kk][row + 0] = v.x; As[kk][row + 1] = v.y;
      As[kk][row + 2] = v.z; As[kk][row + 3] = v.w;
    }
#pragma unroll
    for (int p = 0; p < 2; ++p) {
      int id = tid + p * 256;
      int row = id >> 2, c4 = id & 3;
      float4 v = *(const float4*)(W + (size_t)(n0 + row) * Hh + k0 + c4 * 4);
      Bs[c4 * 4 + 0][row] = v.x; Bs[c4 * 4 + 1][row] = v.y;
      Bs[c4 * 4 + 2][row] = v.z; Bs[c4 * 4 + 3][row] = v.w;
    }
    __syncthreads();
#pragma unroll
    for (int kk = 0; kk < 16; ++kk) {
      float4 a0 = *(const float4*)&As[kk][tm * 8];
      float4 a1 = *(const float4*)&As[kk][tm * 8 + 4];
      float4 b0 = *(const float4*)&Bs[kk][tn * 8];
      float4 b1 = *(const float4*)&Bs[kk][tn * 8 + 4];
      float av[8] = {a0.x, a0.y, a0.z, a0.w, a1.x, a1.y, a1.z, a1.w};
      float bv[8] = {b0.x, b0.y, b0.z, b0.w, b1.x, b1.y, b1.z, b1.w};
#pragma unroll
      for (int i = 0; i < 8; ++i)
#pragma unroll
        for (int j = 0; j < 8; ++j)
          acc[i][j] = fmaf(av[i], bv[j], acc[i][j]);
    }
    __syncthreads();
  }
#pragma unroll
  for (int i = 0; i < 8; ++i) {
    int m = m0 + tm * 8 + i;
    int t = m >> 6, b = m & 63;
    size_t rowo = (size_t)(b * Tt + t) * Vv;
#pragma unroll
    for (int jj = 0; jj < 2; ++jj) {
      int n = n0 + tn * 8 + jj * 4;
      float4 v;
      v.x = acc[i][jj * 4 + 0] + bias[n + 0];
      v.y = acc[i][jj * 4 + 1] + bias[n + 1];
      v.z = acc[i][jj * 4 + 2] + bias[n + 2];
      v.w = acc[i][jj * 4 + 3] + bias[n + 3];
      *(float4*)&C[rowo + n] = v;
    }
  }
}

__global__ void k_zero(unsigned* __restrict__ f) {
  int g = blockIdx.x * 256 + threadIdx.x;
  if (g < NGRP * FSTR + FSTR) f[g] = 0u;
}

// ---------------- relaxed-only two-hop grid barrier ------------------------------------
// (unchanged from round 3 — proven) No acquire/release -> no L2 wb/inv. All cross-block
// data is either sc0|sc1 (LLC-coherent) or write-once addresses (no stale line possible).
__device__ __forceinline__ void gbar(unsigned* __restrict__ gc, unsigned bar,
                                     int tid, int blk) {
  unsigned* flag = gc + (size_t)NGRP * FSTR;
  __syncthreads();   // drains vmcnt(0): all data stores committed
  if (tid == 0)
    __hip_atomic_fetch_add(gc + (size_t)(blk & (NGRP - 1)) * FSTR, 1u,
                           __ATOMIC_RELAXED, __HIP_MEMORY_SCOPE_AGENT);
  if (blk == 0) {
    if (tid < NGRP) {
      unsigned tgt = bar * (NBLK / NGRP);
      while (!__all(__hip_atomic_load(gc + (size_t)tid * FSTR, __ATOMIC_RELAXED,
                                      __HIP_MEMORY_SCOPE_AGENT) >= tgt)) { }
    }
    __syncthreads();             // all 64 observations precede the flag store
    if (tid == 0)
      __hip_atomic_store(flag, bar, __ATOMIC_RELAXED, __HIP_MEMORY_SCOPE_AGENT);
  } else if (tid == 0) {
    while (__hip_atomic_load(flag, __ATOMIC_RELAXED, __HIP_MEMORY_SCOPE_AGENT) < bar) { }
  }
  __asm__ __volatile__("" ::: "memory");  // no load hoisting above the spin
  __syncthreads();
}

// ---------------- persistent recurrence ------------------------------------------------
// 256 blocks x 1024 threads. ht_all[t][n][b] write-once (cached reads safe).
// rh: if rh_str!=0, rh_all[t][n][b] is ALSO write-once -> phase B uses normal cached
// loads (per-XCD: LLC first-touch + L2 broadcast) instead of 32x LLC re-reads.
// If rh_str==0 (workspace fallback), single rh buffer accessed sc1-only as in round 3.
__global__ __launch_bounds__(1024) void k_recur(float* __restrict__ ht_all,
                                                float* __restrict__ rh_all,
                                                int rh_big,
                                                float* __restrict__ pre_z,
                                                const float* __restrict__ AtT_r,
                                                const float* __restrict__ AtT_z,
                                                const float* __restrict__ AtT_b,
                                                const float* __restrict__ Wr,
                                                const float* __restrict__ Wz,
                                                const float* __restrict__ Wbar,
                                                const float* __restrict__ start,
                                                unsigned* __restrict__ gcnt) {
  __shared__ float red[NWV * 8 * 64];    // 32 KB
  int tid = threadIdx.x;
  int lane = tid & 63;
  int wv = __builtin_amdgcn_readfirstlane(tid >> 6);
  int blk = blockIdx.x;
  int rc = tid >> 6, rb = tid & 63;      // reduce-phase mapping (col, batch)
  size_t rh_str = rh_big ? (size_t)(Hh * Bb) : 0;
  unsigned bar = 0;

  {  // slice 0 = broadcast(start), pushed to LLC
    int g = blk * 1024 + tid;
    if (g < Hh * Bb) DEV_STORE(ht_all + g, start[g >> 6]);
  }
  gbar(gcnt, ++bar, tid, blk);

  for (int t = 0; t < Tt; ++t) {
    const float* hcur = ht_all + (size_t)t * 65536;   // slice t: write-once, cached ok
    float* rh_t = rh_all + (size_t)t * rh_str;
    // ---------------- phase A: r,z preactivations ----------------
    {
      int n0 = blk * 8;                       // 0..2047 across [r|z]
      float at_pre = 0.f, h_pre = 0.f;
      if (tid < 512) {
        int rn = n0 + rc;
        if (blk < 128) {
          at_pre = AtT_r[(size_t)t * 65536 + rn * 64 + rb];
          h_pre  = hcur[rn * 64 + rb];
        } else {
          at_pre = AtT_z[(size_t)t * 65536 + (rn - 1024) * 64 + rb];
        }
      }
      int k0 = wv * 64;
      const float* Wsel = (blk < 128) ? Wr : Wz;
      int nb = (blk < 128) ? n0 : n0 - 1024;
      const float* hk = hcur + k0 * 64 + lane;
      const float* wbase = Wsel + (size_t)nb * 1536 + 512 + k0;
      float acc[8];
#pragma unroll
      for (int c = 0; c < 8; ++c) acc[c] = 0.f;
#pragma unroll 8
      for (int kk = 0; kk < 64; ++kk) {
        float vh = hk[kk * 64];
#pragma unroll
        for (int c = 0; c < 8; ++c)
          acc[c] = fmaf(wbase[(size_t)c * 1536 + kk], vh, acc[c]);
      }
#pragma unroll
      for (int c = 0; c < 8; ++c) red[(wv * 8 + c) * 64 + lane] = acc[c];
      __syncthreads();
      if (tid < 512) {
        float s = 0.f;
#pragma unroll
        for (int w = 0; w < NWV; ++w) s += red[(w * 8 + rc) * 64 + rb];
        int n = n0 + rc;
        s += at_pre;
        if (blk < 128) {
          float sg = 1.f / (1.f + __expf(-s));
          DEV_STORE(rh_t + n * 64 + rb, sg * h_pre);
        } else {
          DEV_STORE(pre_z + (n - 1024) * 64 + rb, s);
        }
      }
    }
    gbar(gcnt, ++bar, tid, blk);
    // ---------------- phase B: hbar + fused update ----------------
    {
      int n0 = blk * 4;                       // 0..1023
      float at_pre = 0.f, pz_pre = 0.f, ho_pre = 0.f;
      if (tid < 256) {
        int n = n0 + rc;
        at_pre = AtT_b[(size_t)t * 65536 + n * 64 + rb];
        pz_pre = DEV_LOAD(pre_z + n * 64 + rb);
        ho_pre = hcur[n * 64 + rb];
      }
      int k0 = wv * 64;
      const float* hk = rh_t + k0 * 64 + lane;
      const float* wbase = Wbar + (size_t)n0 * 1536 + 512 + k0;
      float acc[4];
#pragma unroll
      for (int c = 0; c < 4; ++c) acc[c] = 0.f;
      if (rh_big) {
#pragma unroll 8
        for (int kk = 0; kk < 64; ++kk) {
          float vh = hk[kk * 64];              // normal cached load (write-once slice)
#pragma unroll
          for (int c = 0; c < 4; ++c)
            acc[c] = fmaf(wbase[(size_t)c * 1536 + kk], vh, acc[c]);
        }
      } else {
#pragma unroll 8
        for (int kk = 0; kk < 64; ++kk) {
          float vh = DEV_LOAD(hk + kk * 64);   // LLC read-through (reused address)
#pragma unroll
          for (int c = 0; c < 4; ++c)
            acc[c] = fmaf(wbase[(size_t)c * 1536 + kk], vh, acc[c]);
        }
      }
#pragma unroll
      for (int c = 0; c < 4; ++c) red[(wv * 4 + c) * 64 + lane] = acc[c];
      __syncthreads();
      if (tid < 256) {
        float s = 0.f;
#pragma unroll
        for (int w = 0; w < NWV; ++w) s += red[(w * 4 + rc) * 64 + rb];
        int n = n0 + rc;
        s += at_pre;
        float e = __expf(2.f * s);
        float hbt = 1.f - 2.f / (e + 1.f);    // tanh, saturation-safe
        float z = 1.f / (1.f + __expf(-pz_pre));
        float hn = ho_pre + z * (hbt - ho_pre);
        DEV_STORE(ht_all + (size_t)(t + 1) * 65536 + n * 64 + rb, hn);
      }
    }
    gbar(gcnt, ++bar, tid, blk);
  }
}

extern "C" void kernel_launch(void* const* d_in, const int* in_sizes, int n_in,
                              void* d_out, int out_size, void* d_ws, size_t ws_size,
                              hipStream_t stream) {
  (void)in_sizes; (void)n_in; (void)out_size;
  const int*   x     = (const int*)  d_in[0];
  const float* start = (const float*)d_in[1];
  const float* wte   = (const float*)d_in[2];
  const float* Wr    = (const float*)d_in[3];
  const float* br    = (const float*)d_in[4];
  const float* Wbar  = (const float*)d_in[5];
  const float* bbar  = (const float*)d_in[6];
  const float* Wz    = (const float*)d_in[7];
  const float* bz    = (const float*)d_in[8];
  const float* Whead = (const float*)d_in[9];
  const float* bhead = (const float*)d_in[10];
  float* out = (float*)d_out;

  const size_t fA = (size_t)Tt * Hh * Bb;          // 16.78M floats
  const size_t fH = (size_t)Hh * Bb;               // 65536 floats
  const size_t gcnt_u32 = NGRP * FSTR + FSTR;
  // big layout: 3*AtT + ht_all + rh_all(T slices) + pre_z + gcnt
  size_t need_big = (3 * fA + (Tt + 1) * fH + fA + fH) * 4 + gcnt_u32 * 4;
  int rh_big = (ws_size >= need_big) ? 1 : 0;

  float* p = (float*)d_ws;
  float* AtT_r  = p; p += fA;
  float* AtT_z  = p; p += fA;
  float* AtT_b  = p; p += fA;
  float* ht_all = p; p += (size_t)(Tt + 1) * fH;   // slice 0 = h0; slices 1..T = hidden
  float* rh_all = p; p += rh_big ? fA : fH;        // T write-once slices, or 1 sc1 buffer
  float* pre_z  = p; p += fH;
  unsigned* gcnt = (unsigned*)p;

  dim3 b256(256);
  k_zero<<<dim3((NGRP * FSTR + FSTR + 255) / 256), b256, 0, stream>>>(gcnt);
  k_proj<<<dim3(128, 8), b256, 0, stream>>>(x, wte, Wr,   br,   AtT_r);
  k_proj<<<dim3(128, 8), b256, 0, stream>>>(x, wte, Wz,   bz,   AtT_z);
  k_proj<<<dim3(128, 8), b256, 0, stream>>>(x, wte, Wbar, bbar, AtT_b);

  void* args[] = {&ht_all, &rh_all, &rh_big, &pre_z, &AtT_r, &AtT_z, &AtT_b,
                  (void*)&Wr, (void*)&Wz, (void*)&Wbar, (void*)&start, &gcnt};
  hipLaunchCooperativeKernel((void*)k_recur, dim3(NBLK), dim3(1024), args, 0, stream);

  k_head<<<dim3(128, 32), b256, 0, stream>>>(ht_all + fH, Whead, bhead, out);
}